// Round 5
// baseline (622.308 us; speedup 1.0000x reference)
//
#include <hip/hip_runtime.h>

// Problem constants (fixed by setup_inputs) — all tensors fp32 on the wire.
#define C_CH  512
#define R_CH  128
#define BATCH 8
#define HW    16384                 // 128*128
#define HW4   (HW / 4)              // 4096 float4 per plane
#define TPB   512                   // 8 waves/block
#define NBLK  256                   // one block per CU: co-residency by construction
#define F4PT  16                    // HW4 / 256 (256 threads per plane-half)

// Native vector type — nontemporal builtins reject HIP_vector_type.
typedef float floatx4 __attribute__((ext_vector_type(4)));

__device__ __forceinline__ float relu6f(float v) {
    return fminf(fmaxf(v, 0.0f), 6.0f);
}

// Single persistent kernel, manual grid barrier. Block bid owns channels
// {2bid, 2bid+1}. Per phase j: planes of batch pair {2j,2j+1} live in
// registers (A,B: 32 float4), means reduced + published, grid barrier,
// redundant tiny MLP, add + nt-store from registers. x read from HBM ONCE.
__global__ __launch_bounds__(TPB, 2) void fused_all(
    const float4* __restrict__ x,
    const float* __restrict__ wg,      // [R_CH, C_CH]
    const float* __restrict__ wf,      // [C_CH, R_CH]
    const float* __restrict__ gamma,
    const float* __restrict__ beta,
    const float* __restrict__ mu,
    const float* __restrict__ var,
    float* __restrict__ meanv,         // ws: [BATCH][C_CH]
    unsigned* __restrict__ bar,        // ws: 4 counters, pre-zeroed
    floatx4* __restrict__ out)
{
    const int tid  = threadIdx.x;
    const int half = tid >> 8;          // 0/1 → which of the block's 2 channels
    const int t2   = tid & 255;
    const int c    = 2 * (int)blockIdx.x + half;

    __shared__ float red[2][2][256];    // [half][batch-of-pair][thread]
    __shared__ float part[2][TPB];      // MLP partials per batch
    __shared__ float m0[C_CH], m1[C_CH];
    __shared__ float ts[2][R_CH];
    __shared__ float ys[2][2];          // [half][batch-of-pair]

    float4 A[F4PT], B[F4PT];            // register-held pair of planes

#define LOAD_AND_MEAN(B0, B1)                                                 \
    {                                                                          \
        const float4* pa = x + ((size_t)((B0) * C_CH + c)) * HW4;              \
        const float4* pb = x + ((size_t)((B1) * C_CH + c)) * HW4;              \
        _Pragma("unroll")                                                      \
        for (int k = 0; k < F4PT; ++k) A[k] = pa[t2 + k * 256];                \
        _Pragma("unroll")                                                      \
        for (int k = 0; k < F4PT; ++k) B[k] = pb[t2 + k * 256];                \
        float sA = 0.f, sB = 0.f;                                              \
        _Pragma("unroll")                                                      \
        for (int k = 0; k < F4PT; ++k) sA += (A[k].x + A[k].y) + (A[k].z + A[k].w); \
        _Pragma("unroll")                                                      \
        for (int k = 0; k < F4PT; ++k) sB += (B[k].x + B[k].y) + (B[k].z + B[k].w); \
        red[half][0][t2] = sA; red[half][1][t2] = sB;                          \
        __syncthreads();                                                       \
        for (int off = 128; off > 0; off >>= 1) {                              \
            if (t2 < off) {                                                    \
                red[half][0][t2] += red[half][0][t2 + off];                    \
                red[half][1][t2] += red[half][1][t2 + off];                    \
            }                                                                  \
            __syncthreads();                                                   \
        }                                                                      \
        if (t2 == 0) {                                                         \
            meanv[(B0) * C_CH + c] = red[half][0][0] * (1.0f / (float)HW);     \
            meanv[(B1) * C_CH + c] = red[half][1][0] * (1.0f / (float)HW);     \
        }                                                                      \
    }

#define GRID_BARRIER(J)                                                        \
    {                                                                          \
        __syncthreads(); /* drains all block stores (vmcnt) before fence */    \
        if (tid == 0) {                                                        \
            __threadfence();            /* release: L2 writeback */            \
            atomicAdd(&bar[(J)], 1u);   /* device-scope arrival */             \
            while (__hip_atomic_load(&bar[(J)], __ATOMIC_RELAXED,              \
                                     __HIP_MEMORY_SCOPE_AGENT) < NBLK)         \
                __builtin_amdgcn_s_sleep(2);                                   \
            __threadfence();            /* acquire: invalidate */              \
        }                                                                      \
        __syncthreads();                                                       \
    }

    // ---- prologue: batch pair {0,1} ----
    LOAD_AND_MEAN(0, 1)
    GRID_BARRIER(0)

    for (int j = 0; j < 4; ++j) {
        const int b0 = 2 * j, b1 = b0 + 1;

        // Stage means to LDS (agent-scope loads bypass any stale cache).
        for (int k = tid; k < C_CH; k += TPB) {
            m0[k] = __hip_atomic_load(&meanv[b0 * C_CH + k], __ATOMIC_RELAXED,
                                      __HIP_MEMORY_SCOPE_AGENT);
            m1[k] = __hip_atomic_load(&meanv[b1 * C_CH + k], __ATOMIC_RELAXED,
                                      __HIP_MEMORY_SCOPE_AGENT);
        }
        __syncthreads();

        // t[r] = relu6(wg[r,:]·m) for both batches: 4 threads/row, quarter-row each.
        {
            const int r = tid & (R_CH - 1);
            const int q = tid >> 7;                 // 0..3
            const float4* w4 = (const float4*)(wg + (size_t)r * C_CH) + q * (C_CH / 16);
            const float* mh0 = m0 + q * (C_CH / 4);
            const float* mh1 = m1 + q * (C_CH / 4);
            float a0 = 0.f, a1 = 0.f;
#pragma unroll
            for (int i = 0; i < C_CH / 16; ++i) {   // 32 float4 = 128 floats
                float4 v = w4[i];
                const int k4 = i * 4;
                a0 += v.x * mh0[k4] + v.y * mh0[k4 + 1] + v.z * mh0[k4 + 2] + v.w * mh0[k4 + 3];
                a1 += v.x * mh1[k4] + v.y * mh1[k4 + 1] + v.z * mh1[k4 + 2] + v.w * mh1[k4 + 3];
            }
            part[0][tid] = a0; part[1][tid] = a1;
        }
        __syncthreads();
        if (tid < R_CH) {
            ts[0][tid] = relu6f(part[0][tid] + part[0][tid + 128] +
                                part[0][tid + 256] + part[0][tid + 384]);
        } else if (tid < 2 * R_CH) {
            const int r = tid - R_CH;
            ts[1][r] = relu6f(part[1][r] + part[1][r + 128] +
                              part[1][r + 256] + part[1][r + 384]);
        }
        __syncthreads();

        // y = relu6(BN(wf[c,:]·t)) — wave 0 → channel 2bid, wave 1 → 2bid+1.
        if (tid < 128) {
            const int ch = tid >> 6;
            const int l  = tid & 63;
            const int cc = 2 * (int)blockIdx.x + ch;
            const float2 w2 = ((const float2*)(wf + (size_t)cc * R_CH))[l];
            float s0 = w2.x * ts[0][2 * l] + w2.y * ts[0][2 * l + 1];
            float s1 = w2.x * ts[1][2 * l] + w2.y * ts[1][2 * l + 1];
            for (int off = 32; off > 0; off >>= 1) {
                s0 += __shfl_down(s0, off);
                s1 += __shfl_down(s1, off);
            }
            if (l == 0) {
                const float is = 1.0f / sqrtf(var[cc] + 1e-5f);
                const float sc = gamma[cc] * is;
                const float bi = beta[cc] - mu[cc] * sc;
                ys[ch][0] = relu6f(s0 * sc + bi);
                ys[ch][1] = relu6f(s1 * sc + bi);
            }
        }
        __syncthreads();
        const float y0 = ys[half][0];
        const float y1 = ys[half][1];

        // Stream adds from registers (nt stores — write stream never allocates).
        {
            floatx4* po0 = out + ((size_t)(b0 * C_CH + c)) * HW4;
            floatx4* po1 = out + ((size_t)(b1 * C_CH + c)) * HW4;
#pragma unroll
            for (int k = 0; k < F4PT; ++k) {
                floatx4 w;
                w.x = A[k].x + y0; w.y = A[k].y + y0; w.z = A[k].z + y0; w.w = A[k].w + y0;
                __builtin_nontemporal_store(w, po0 + t2 + k * 256);
            }
#pragma unroll
            for (int k = 0; k < F4PT; ++k) {
                floatx4 w;
                w.x = B[k].x + y1; w.y = B[k].y + y1; w.z = B[k].z + y1; w.w = B[k].w + y1;
                __builtin_nontemporal_store(w, po1 + t2 + k * 256);
            }
        }

        // Prefetch next pair, publish its means, barrier (overlaps the writes).
        if (j < 3) {
            LOAD_AND_MEAN(b0 + 2, b1 + 2)
            GRID_BARRIER(j + 1)
        }
    }
#undef LOAD_AND_MEAN
#undef GRID_BARRIER
}

extern "C" void kernel_launch(void* const* d_in, const int* in_sizes, int n_in,
                              void* d_out, int out_size, void* d_ws, size_t ws_size,
                              hipStream_t stream) {
    const float4* x4   = (const float4*)d_in[0];
    const float* wg    = (const float*)d_in[1];
    const float* wf    = (const float*)d_in[2];
    const float* gamma = (const float*)d_in[3];
    const float* beta  = (const float*)d_in[4];
    const float* mu    = (const float*)d_in[5];
    const float* var   = (const float*)d_in[6];

    unsigned* bar = (unsigned*)d_ws;             // 4 counters (64 B reserved)
    float* meanv  = (float*)d_ws + 64;           // [BATCH][C_CH] floats
    floatx4* out  = (floatx4*)d_out;

    hipMemsetAsync(d_ws, 0, 64, stream);         // zero barrier counters
    fused_all<<<NBLK, TPB, 0, stream>>>(x4, wg, wf, gamma, beta, mu, var,
                                        meanv, bar, out);
}